// Round 7
// baseline (919.409 us; speedup 1.0000x reference)
//
#include <hip/hip_runtime.h>
#include <hip/hip_bf16.h>

typedef unsigned int u32;
typedef short bf16x8 __attribute__((ext_vector_type(8)));
typedef float floatx4 __attribute__((ext_vector_type(4)));

#define NNODES 50000
#define NEDGES 800000
#define INSZ   1024
#define EMB    500
#define EMBP   512

__device__ __forceinline__ short f2bf(float f) {
    u32 u = __builtin_bit_cast(u32, f);
    u32 r = u + 0x7FFFu + ((u >> 16) & 1u);   // round-to-nearest-even
    return (short)(r >> 16);
}
__device__ __forceinline__ float bf2f(short h) {
    u32 u = ((u32)(unsigned short)h) << 16;
    return __builtin_bit_cast(float, u);
}

#define GLDS16(gp, lp) __builtin_amdgcn_global_load_lds( \
    (const __attribute__((address_space(1))) u32*)(gp),  \
    (__attribute__((address_space(3))) u32*)(lp), 16, 0, 0)

// Bijective XCD-chunked swizzle (m204). Both GEMM grids are %8==0 (r=0).
__device__ __forceinline__ u32 xcd_swz(u32 orig, u32 q, u32 r) {
    u32 xcd = orig & 7u, seq = orig >> 3;
    u32 base = (xcd < r) ? xcd * (q + 1u) : r * (q + 1u) + (xcd - r) * q;
    return base + seq;
}

// ---------------------------------------------------------------------------
// prep: fused {conv_x | pack_all | count_edges} — mutually independent work.
// grid = 25000 blocks x 256.
//   all blocks     : X fp32 -> bf16 (8 elems/thread)
//   blocks < 2048  : weight packing (wencP [512][1024], wdecP [1024][512],
//                    Bw [1024][512])
//   blocks < 3125  : dst histogram (counts)
// ---------------------------------------------------------------------------
__global__ __launch_bounds__(256)
void prep(const float* __restrict__ X, const float* __restrict__ wenc,
          const float* __restrict__ conv, const float* __restrict__ lin,
          const float* __restrict__ wdec, const int* __restrict__ dst,
          short* __restrict__ Xb, short* __restrict__ wencP,
          short* __restrict__ wdecP, short* __restrict__ Bw,
          int* __restrict__ counts) {
    const int b = blockIdx.x;
    const int gid = b * 256 + threadIdx.x;
    {   // conv_x
        size_t base = (size_t)gid * 8;
        floatx4 f0 = *(const floatx4*)(X + base);
        floatx4 f1 = *(const floatx4*)(X + base + 4);
        bf16x8 p;
#pragma unroll
        for (int j = 0; j < 4; ++j) { p[j] = f2bf(f0[j]); p[4 + j] = f2bf(f1[j]); }
        *(bf16x8*)(Xb + base) = p;
    }
    if (b < 2048) {
        {   // wencP [512][1024]
            int m = gid >> 10, k = gid & 1023;
            wencP[gid] = (m < EMB) ? f2bf(wenc[m * INSZ + k]) : (short)0;
        }
        {   // wdecP [1024][512]
            int m = gid >> 9, k = gid & 511;
            wdecP[gid] = (k < EMB) ? f2bf(wdec[m * EMB + k]) : (short)0;
        }
        {   // Bw [1024][512]: kk<512 -> conv[kk][j]; kk>=512 -> lin[j][kk-512]
            int kk = gid >> 9, j = gid & 511;
            short v = 0;
            if (j < EMB) {
                if (kk < EMB)                          v = f2bf(conv[kk * EMB + j]);
                else if (kk >= 512 && kk - 512 < EMB)  v = f2bf(lin[j * EMB + (kk - 512)]);
            }
            Bw[gid] = v;
        }
    }
    if (b < 3125) {   // count_edges
        atomicAdd(&counts[dst[gid]], 1);
    }
}

// ---------------------------------------------------------------------------
// Wbig precompute: Wbig[m][kk] = sum_j wdecP[m][j] * Bw[kk][j].
// 128x128 tile, 4 waves, BK=32, double-buffered. M=N=1024, K=512.
// ---------------------------------------------------------------------------
__global__ __launch_bounds__(256)
void gemm_wpre(const short* __restrict__ Ap, const short* __restrict__ Bp,
               short* __restrict__ Wbig) {
    __shared__ short As[2][128 * 32];
    __shared__ short Bs[2][128 * 32];
    const int tid  = threadIdx.x;
    const int lane = tid & 63;
    const int wave = tid >> 6;
    const int wr   = (wave >> 1) * 64;
    const int wc   = (wave & 1) * 64;
    const int rowBase = blockIdx.y * 128;
    const int colBase = blockIdx.x * 128;

    floatx4 acc[4][4] = {};

    const int r0 = tid >> 2;
    const int c0 = (tid & 3) * 8;
    const short* aP0 = Ap + (size_t)(rowBase + r0) * EMBP + c0;
    const short* aP1 = Ap + (size_t)(rowBase + r0 + 64) * EMBP + c0;
    const short* bP0 = Bp + (size_t)(colBase + r0) * EMBP + c0;
    const short* bP1 = Bp + (size_t)(colBase + r0 + 64) * EMBP + c0;

    const int q8  = (lane >> 4) * 8;
    const int m16 = lane & 15;

#define STAGE_W(buf, k0)                                   \
    GLDS16(aP0 + (k0), &As[buf][tid * 8]);                 \
    GLDS16(aP1 + (k0), &As[buf][2048 + tid * 8]);          \
    GLDS16(bP0 + (k0), &Bs[buf][tid * 8]);                 \
    GLDS16(bP1 + (k0), &Bs[buf][2048 + tid * 8]);

    STAGE_W(0, 0);
    __syncthreads();
    int cur = 0;
    for (int t = 0; t < 16; ++t) {
        if (t + 1 < 16) { STAGE_W(cur ^ 1, (t + 1) * 32); }
        bf16x8 af[4], bfr[4];
#pragma unroll
        for (int i = 0; i < 4; ++i) {
            af[i]  = *(const bf16x8*)&As[cur][(wr + i * 16 + m16) * 32 + q8];
            bfr[i] = *(const bf16x8*)&Bs[cur][(wc + i * 16 + m16) * 32 + q8];
        }
#pragma unroll
        for (int i = 0; i < 4; ++i)
#pragma unroll
            for (int j = 0; j < 4; ++j)
                acc[i][j] = __builtin_amdgcn_mfma_f32_16x16x32_bf16(af[i], bfr[j], acc[i][j], 0, 0, 0);
        __syncthreads();
        cur ^= 1;
    }
#undef STAGE_W

    const int rq = (lane >> 4) * 4;
#pragma unroll
    for (int i = 0; i < 4; ++i)
#pragma unroll
        for (int j = 0; j < 4; ++j)
#pragma unroll
            for (int reg = 0; reg < 4; ++reg) {
                int row = rowBase + wr + i * 16 + rq + reg;
                int col = colBase + wc + j * 16 + m16;
                Wbig[(size_t)row * 1024 + col] = f2bf(acc[i][j][reg]);
            }
}

// ---------------------------------------------------------------------------
// 256x256-tile 2-phase GEMMs: 512 thr = 8 waves (2M x 4N of 128x64), BK=32,
// double-buffered LDS (64KB), prefetch-next-before-compute, ONE barrier per
// k-step. 32 MFMA per 4 GLDS per k-step (2x the 128² arithmetic intensity).
// C/D layout: col=lane&15, row=(lane>>4)*4+reg.
// ---------------------------------------------------------------------------

// ---- encoder: h[n,m] = sigmoid( sum_k xb[n,k]*wencP[m,k] + benc[m] ) ------
// grid = 392 (196 row-tiles x 2 col-tiles), %8==0.
__global__ __launch_bounds__(512)
void gemm_enc(const short* __restrict__ Xb, const short* __restrict__ Wp,
              const float* __restrict__ benc, short* __restrict__ H) {
    __shared__ short As[2][256 * 32];
    __shared__ short Bs[2][256 * 32];
    const int tid  = threadIdx.x;
    const int lane = tid & 63;
    const int wave = tid >> 6;
    const int wm   = wave >> 2;          // 0..1  -> 128-row band
    const int wn   = wave & 3;           // 0..3  -> 64-col band
    const u32 swz  = xcd_swz(blockIdx.x, 49, 0);        // nwg=392
    const int rowBase = (int)(swz >> 1) * 256;
    const int colBase = (int)(swz & 1) * 256;

    floatx4 acc[8][4] = {};

    const int r0 = tid >> 2;             // 0..127
    const int c0 = (tid & 3) * 8;
    int ar0 = rowBase + r0;        if (ar0 >= NNODES) ar0 = NNODES - 1;
    int ar1 = rowBase + r0 + 128;  if (ar1 >= NNODES) ar1 = NNODES - 1;
    const short* aP0 = Xb + (size_t)ar0 * INSZ + c0;
    const short* aP1 = Xb + (size_t)ar1 * INSZ + c0;
    const short* bP0 = Wp + (size_t)(colBase + r0) * INSZ + c0;
    const short* bP1 = Wp + (size_t)(colBase + r0 + 128) * INSZ + c0;

    const int q8  = (lane >> 4) * 8;
    const int m16 = lane & 15;

#define STAGE_E(buf, k0)                                   \
    GLDS16(aP0 + (k0), &As[buf][tid * 8]);                 \
    GLDS16(aP1 + (k0), &As[buf][4096 + tid * 8]);          \
    GLDS16(bP0 + (k0), &Bs[buf][tid * 8]);                 \
    GLDS16(bP1 + (k0), &Bs[buf][4096 + tid * 8]);

    STAGE_E(0, 0);
    __syncthreads();
    int cur = 0;
    for (int t = 0; t < 32; ++t) {
        if (t + 1 < 32) { STAGE_E(cur ^ 1, (t + 1) * 32); }
        bf16x8 af[8], bfr[4];
#pragma unroll
        for (int i = 0; i < 8; ++i)
            af[i]  = *(const bf16x8*)&As[cur][(wm * 128 + i * 16 + m16) * 32 + q8];
#pragma unroll
        for (int j = 0; j < 4; ++j)
            bfr[j] = *(const bf16x8*)&Bs[cur][(wn * 64 + j * 16 + m16) * 32 + q8];
#pragma unroll
        for (int i = 0; i < 8; ++i)
#pragma unroll
            for (int j = 0; j < 4; ++j)
                acc[i][j] = __builtin_amdgcn_mfma_f32_16x16x32_bf16(af[i], bfr[j], acc[i][j], 0, 0, 0);
        __syncthreads();
        cur ^= 1;
    }
#undef STAGE_E

    const int rq = (lane >> 4) * 4;
#pragma unroll
    for (int i = 0; i < 8; ++i)
#pragma unroll
        for (int j = 0; j < 4; ++j)
#pragma unroll
            for (int reg = 0; reg < 4; ++reg) {
                int row = rowBase + wm * 128 + i * 16 + rq + reg;
                int col = colBase + wn * 64 + j * 16 + m16;
                if (row < NNODES) {
                    float b = (col < EMB) ? benc[col] : 0.f;
                    float v = 1.f / (1.f + __expf(-(acc[i][j][reg] + b)));
                    H[(size_t)row * EMBP + col] = f2bf(v);
                }
            }
}

// ---- fused mid+dec: out[n,m] = sum_{k<512} aggB[n,k]*Wbig[m][k]
//                              + sum_{k<512} h[n,k]*Wbig[m][512+k] + bdec[m]
// grid = 784 (196 row-tiles x 4 col-tiles), %8==0.
__global__ __launch_bounds__(512)
void gemm_fused(const short* __restrict__ AggB, const short* __restrict__ H,
                const short* __restrict__ Wb, const float* __restrict__ bdec,
                float* __restrict__ Out) {
    __shared__ short As[2][256 * 32];
    __shared__ short Bs[2][256 * 32];
    const int tid  = threadIdx.x;
    const int lane = tid & 63;
    const int wave = tid >> 6;
    const int wm   = wave >> 2;
    const int wn   = wave & 3;
    const u32 swz  = xcd_swz(blockIdx.x, 98, 0);        // nwg=784
    const int rowBase = (int)(swz >> 2) * 256;
    const int colBase = (int)(swz & 3) * 256;

    floatx4 acc[8][4] = {};

    const int r0 = tid >> 2;
    const int c0 = (tid & 3) * 8;
    int ar0 = rowBase + r0;        if (ar0 >= NNODES) ar0 = NNODES - 1;
    int ar1 = rowBase + r0 + 128;  if (ar1 >= NNODES) ar1 = NNODES - 1;
    const short* agP0 = AggB + (size_t)ar0 * EMBP + c0;
    const short* agP1 = AggB + (size_t)ar1 * EMBP + c0;
    const short* hP0  = H + (size_t)ar0 * EMBP + c0;
    const short* hP1  = H + (size_t)ar1 * EMBP + c0;
    const short* wP0  = Wb + (size_t)(colBase + r0) * 1024 + c0;
    const short* wP1  = Wb + (size_t)(colBase + r0 + 128) * 1024 + c0;

    const int q8  = (lane >> 4) * 8;
    const int m16 = lane & 15;

#define STAGE_F(buf, k0)                                              \
    if ((k0) < 512) {                                                 \
        GLDS16(agP0 + (k0), &As[buf][tid * 8]);                       \
        GLDS16(agP1 + (k0), &As[buf][4096 + tid * 8]);                \
    } else {                                                          \
        GLDS16(hP0 + ((k0) - 512), &As[buf][tid * 8]);                \
        GLDS16(hP1 + ((k0) - 512), &As[buf][4096 + tid * 8]);         \
    }                                                                 \
    GLDS16(wP0 + (k0), &Bs[buf][tid * 8]);                            \
    GLDS16(wP1 + (k0), &Bs[buf][4096 + tid * 8]);

    STAGE_F(0, 0);
    __syncthreads();
    int cur = 0;
    for (int t = 0; t < 32; ++t) {
        if (t + 1 < 32) { STAGE_F(cur ^ 1, (t + 1) * 32); }
        bf16x8 af[8], bfr[4];
#pragma unroll
        for (int i = 0; i < 8; ++i)
            af[i]  = *(const bf16x8*)&As[cur][(wm * 128 + i * 16 + m16) * 32 + q8];
#pragma unroll
        for (int j = 0; j < 4; ++j)
            bfr[j] = *(const bf16x8*)&Bs[cur][(wn * 64 + j * 16 + m16) * 32 + q8];
#pragma unroll
        for (int i = 0; i < 8; ++i)
#pragma unroll
            for (int j = 0; j < 4; ++j)
                acc[i][j] = __builtin_amdgcn_mfma_f32_16x16x32_bf16(af[i], bfr[j], acc[i][j], 0, 0, 0);
        __syncthreads();
        cur ^= 1;
    }
#undef STAGE_F

    const int rq = (lane >> 4) * 4;
#pragma unroll
    for (int i = 0; i < 8; ++i)
#pragma unroll
        for (int j = 0; j < 4; ++j)
#pragma unroll
            for (int reg = 0; reg < 4; ++reg) {
                int row = rowBase + wm * 128 + i * 16 + rq + reg;
                int col = colBase + wn * 64 + j * 16 + m16;
                if (row < NNODES)
                    Out[(size_t)row * INSZ + col] = acc[i][j][reg] + bdec[col];
            }
}

// ---------------------------------------------------------------------------
// Parallel exclusive scan over counts[50000]: block b re-sums counts[0,b*256)
// (19.6 MB total, L2-resident) then shuffle-scans its own 256. One launch,
// no cross-block dependency.
// ---------------------------------------------------------------------------
__global__ __launch_bounds__(256)
void scan_counts(const int* __restrict__ counts, int* __restrict__ rowPtr,
                 int* __restrict__ cursor) {
    __shared__ int lsum[4];
    __shared__ int wsc[4];
    const int b = blockIdx.x;            // 196 blocks
    const int t = threadIdx.x;
    const int lane = t & 63;
    const int wv = t >> 6;

    int pre = 0;
    for (int i = t; i < b * 256; i += 256) pre += counts[i];
#pragma unroll
    for (int off = 1; off < 64; off <<= 1) pre += __shfl_xor(pre, off, 64);
    if (lane == 0) lsum[wv] = pre;

    int i = b * 256 + t;
    int c = (i < NNODES) ? counts[i] : 0;
    int v = c;
#pragma unroll
    for (int off = 1; off < 64; off <<= 1) {
        int u = __shfl_up(v, off, 64);
        if (lane >= off) v += u;
    }
    if (lane == 63) wsc[wv] = v;
    __syncthreads();

    int base = lsum[0] + lsum[1] + lsum[2] + lsum[3];
    int woff = 0;
    for (int w = 0; w < wv; ++w) woff += wsc[w];
    if (i < NNODES) {
        int p = base + woff + v - c;
        rowPtr[i] = p;
        cursor[i] = p;
    }
}

__global__ __launch_bounds__(256)
void fill_csr(const int* __restrict__ src, const int* __restrict__ dst,
              const float* __restrict__ ew, int* __restrict__ cursor,
              int* __restrict__ csrSrc, float* __restrict__ csrW) {
    int e = blockIdx.x * 256 + threadIdx.x;
    int d = dst[e];
    int p = atomicAdd(&cursor[d], 1);
    csrSrc[p] = src[e];
    csrW[p]   = ew[e];
}

// gather: one wave per destination node; lane owns 8 of 512 cols.
// 8-deep load pipeline (fully unrolled -> all register indices static).
__global__ __launch_bounds__(256)
void aggregate(const short* __restrict__ H, const int* __restrict__ rowPtr,
               const int* __restrict__ counts, const int* __restrict__ csrSrc,
               const float* __restrict__ csrW, short* __restrict__ aggB) {
    const int n    = blockIdx.x * 4 + (threadIdx.x >> 6);
    const int lane = threadIdx.x & 63;
    const int beg  = rowPtr[n];
    const int cnt  = counts[n];
    const short* hb = H + lane * 8;

    float acc[8] = {0.f, 0.f, 0.f, 0.f, 0.f, 0.f, 0.f, 0.f};
    int i = 0;
    for (; i + 8 <= cnt; i += 8) {
        int   s[8]; float w[8]; bf16x8 v[8];
#pragma unroll
        for (int u = 0; u < 8; ++u) { s[u] = csrSrc[beg + i + u]; w[u] = csrW[beg + i + u]; }
#pragma unroll
        for (int u = 0; u < 8; ++u) v[u] = *(const bf16x8*)(hb + (size_t)s[u] * EMBP);
#pragma unroll
        for (int u = 0; u < 8; ++u)
#pragma unroll
            for (int j = 0; j < 8; ++j)
                acc[j] += w[u] * bf2f(v[u][j]);
    }
    for (; i < cnt; ++i) {
        int   s0 = csrSrc[beg + i];
        float w0 = csrW[beg + i];
        bf16x8 v0 = *(const bf16x8*)(hb + (size_t)s0 * EMBP);
#pragma unroll
        for (int j = 0; j < 8; ++j)
            acc[j] += w0 * bf2f(v0[j]);
    }

    bf16x8 o;
#pragma unroll
    for (int j = 0; j < 8; ++j) o[j] = f2bf(acc[j]);
    *(bf16x8*)(aggB + (size_t)n * EMBP + lane * 8) = o;
}

// ---------------------------------------------------------------------------
extern "C" void kernel_launch(void* const* d_in, const int* in_sizes, int n_in,
                              void* d_out, int out_size, void* d_ws, size_t ws_size,
                              hipStream_t stream) {
    const float* x    = (const float*)d_in[0];
    const int*   ei   = (const int*)d_in[1];
    const float* ew   = (const float*)d_in[2];
    const float* wenc = (const float*)d_in[3];
    const float* benc = (const float*)d_in[4];
    const float* wdec = (const float*)d_in[5];
    const float* bdec = (const float*)d_in[6];
    const float* conv = (const float*)d_in[7];
    const float* lin  = (const float*)d_in[8];
    float* out = (float*)d_out;   // [50000][1024] fp32 = 204.8 MB

    // ws layout (107.7 MB):
    //   0        wencP [512][1024]   1 MB
    //   1 MB     wdecP [1024][512]   1 MB
    //   2 MB     Bw    [1024][512]   1 MB
    //   3 MB     Wbig  [1024][1024]  2 MB
    //   5 MB     h     [50000][512]  51.2 MB
    //   56.2 MB  aggB  [50000][512]  51.2 MB  (must NOT alias d_out:
    //            gemm_fused reads it while writing all of d_out)
    char* ws = (char*)d_ws;
    short* wencP = (short*)(ws);
    short* wdecP = (short*)(ws + 1048576);
    short* Bw    = (short*)(ws + 2097152);
    short* Wbig  = (short*)(ws + 3145728);
    short* h     = (short*)(ws + 5242880);
    short* aggB  = (short*)(ws + 5242880 + 51200000);

    // d_out is dead until gemm_fused's final overwrite:
    //   FIRST half  [0, 7MB):       CSR scratch (counts/rowPtr/cursor/csr)
    //   SECOND half [102.4, 204.8): Xbf bf16 [50000][1024]
    // (disjoint -> prep can build counts while writing Xbf)
    char*  scratch = (char*)d_out;
    int*   counts = (int*)scratch;
    int*   rowPtr = counts + NNODES;
    int*   cursor = rowPtr + NNODES;
    int*   csrSrc = cursor + NNODES;
    float* csrW   = (float*)(csrSrc + NEDGES);
    short* Xbf    = (short*)((char*)d_out + 102400000);

    dim3 blk(256);
    hipMemsetAsync(counts, 0, (size_t)NNODES * 4, stream);

    // conv_x + weight packing + dst histogram, one launch
    prep<<<25000, blk, 0, stream>>>(x, wenc, conv, lin, wdec, ei + NEDGES,
                                    Xbf, wencP, wdecP, Bw, counts);

    // Wbig = wdec (x) [conv | lin^T]  (M=N=1024, K=512)
    gemm_wpre<<<dim3(8, 8), blk, 0, stream>>>(wdecP, Bw, Wbig);

    // rowPtr/cursor from counts (parallel, one launch)
    scan_counts<<<196, blk, 0, stream>>>(counts, rowPtr, cursor);
    fill_csr<<<NEDGES / 256, blk, 0, stream>>>(ei, ei + NEDGES, ew, cursor, csrSrc, csrW);

    // h = sigmoid(xb @ wenc^T + benc)
    gemm_enc<<<392, dim3(512), 0, stream>>>(Xbf, wencP, benc, h);

    // agg[n] = sum_{in-edges} w * h[src]
    aggregate<<<NNODES / 4, blk, 0, stream>>>(h, rowPtr, counts, csrSrc, csrW, aggB);

    // out = aggB @ Wbig[:, :512]^T + h @ Wbig[:, 512:]^T + bdec
    gemm_fused<<<784, dim3(512), 0, stream>>>(aggB, h, Wbig, bdec, out);
}

// Round 9
// 878.440 us; speedup vs baseline: 1.0466x; 1.0466x over previous
//
#include <hip/hip_runtime.h>
#include <hip/hip_bf16.h>

typedef unsigned int u32;
typedef short bf16x8 __attribute__((ext_vector_type(8)));
typedef float floatx4 __attribute__((ext_vector_type(4)));

#define NNODES 50000
#define NEDGES 800000
#define INSZ   1024
#define EMB    500
#define EMBP   512

__device__ __forceinline__ short f2bf(float f) {
    u32 u = __builtin_bit_cast(u32, f);
    u32 r = u + 0x7FFFu + ((u >> 16) & 1u);   // round-to-nearest-even
    return (short)(r >> 16);
}
__device__ __forceinline__ float bf2f(short h) {
    u32 u = ((u32)(unsigned short)h) << 16;
    return __builtin_bit_cast(float, u);
}

#define GLDS16(gp, lp) __builtin_amdgcn_global_load_lds( \
    (const __attribute__((address_space(1))) u32*)(gp),  \
    (__attribute__((address_space(3))) u32*)(lp), 16, 0, 0)

// Bijective XCD-chunked swizzle (m204).
__device__ __forceinline__ u32 xcd_swz(u32 orig, u32 q, u32 r) {
    u32 xcd = orig & 7u, seq = orig >> 3;
    u32 base = (xcd < r) ? xcd * (q + 1u) : r * (q + 1u) + (xcd - r) * q;
    return base + seq;
}

// ---------------------------------------------------------------------------
// prep: fused {conv_x | pack_all | count_edges} — mutually independent work.
// grid = 25000 blocks x 256.
// ---------------------------------------------------------------------------
__global__ __launch_bounds__(256)
void prep(const float* __restrict__ X, const float* __restrict__ wenc,
          const float* __restrict__ conv, const float* __restrict__ lin,
          const float* __restrict__ wdec, const int* __restrict__ dst,
          short* __restrict__ Xb, short* __restrict__ wencP,
          short* __restrict__ wdecP, short* __restrict__ Bw,
          int* __restrict__ counts) {
    const int b = blockIdx.x;
    const int gid = b * 256 + threadIdx.x;
    {   // conv_x
        size_t base = (size_t)gid * 8;
        floatx4 f0 = *(const floatx4*)(X + base);
        floatx4 f1 = *(const floatx4*)(X + base + 4);
        bf16x8 p;
#pragma unroll
        for (int j = 0; j < 4; ++j) { p[j] = f2bf(f0[j]); p[4 + j] = f2bf(f1[j]); }
        *(bf16x8*)(Xb + base) = p;
    }
    if (b < 2048) {
        {   // wencP [512][1024]
            int m = gid >> 10, k = gid & 1023;
            wencP[gid] = (m < EMB) ? f2bf(wenc[m * INSZ + k]) : (short)0;
        }
        {   // wdecP [1024][512]
            int m = gid >> 9, k = gid & 511;
            wdecP[gid] = (k < EMB) ? f2bf(wdec[m * EMB + k]) : (short)0;
        }
        {   // Bw [1024][512]: kk<512 -> conv[kk][j]; kk>=512 -> lin[j][kk-512]
            int kk = gid >> 9, j = gid & 511;
            short v = 0;
            if (j < EMB) {
                if (kk < EMB)                          v = f2bf(conv[kk * EMB + j]);
                else if (kk >= 512 && kk - 512 < EMB)  v = f2bf(lin[j * EMB + (kk - 512)]);
            }
            Bw[gid] = v;
        }
    }
    if (b < 3125) {   // count_edges
        atomicAdd(&counts[dst[gid]], 1);
    }
}

// ---------------------------------------------------------------------------
// Wbig precompute: Wbig[m][kk] = sum_j wdecP[m][j] * Bw[kk][j].
// 128x128 tile, 4 waves, BK=32, double-buffered. M=N=1024, K=512.
// ---------------------------------------------------------------------------
__global__ __launch_bounds__(256)
void gemm_wpre(const short* __restrict__ Ap, const short* __restrict__ Bp,
               short* __restrict__ Wbig) {
    __shared__ short As[2][128 * 32];
    __shared__ short Bs[2][128 * 32];
    const int tid  = threadIdx.x;
    const int lane = tid & 63;
    const int wave = tid >> 6;
    const int wr   = (wave >> 1) * 64;
    const int wc   = (wave & 1) * 64;
    const int rowBase = blockIdx.y * 128;
    const int colBase = blockIdx.x * 128;

    floatx4 acc[4][4] = {};

    const int r0 = tid >> 2;
    const int c0 = (tid & 3) * 8;
    const short* aP0 = Ap + (size_t)(rowBase + r0) * EMBP + c0;
    const short* aP1 = Ap + (size_t)(rowBase + r0 + 64) * EMBP + c0;
    const short* bP0 = Bp + (size_t)(colBase + r0) * EMBP + c0;
    const short* bP1 = Bp + (size_t)(colBase + r0 + 64) * EMBP + c0;

    const int q8  = (lane >> 4) * 8;
    const int m16 = lane & 15;

#define STAGE_W(buf, k0)                                   \
    GLDS16(aP0 + (k0), &As[buf][tid * 8]);                 \
    GLDS16(aP1 + (k0), &As[buf][2048 + tid * 8]);          \
    GLDS16(bP0 + (k0), &Bs[buf][tid * 8]);                 \
    GLDS16(bP1 + (k0), &Bs[buf][2048 + tid * 8]);

    STAGE_W(0, 0);
    __syncthreads();
    int cur = 0;
    for (int t = 0; t < 16; ++t) {
        if (t + 1 < 16) { STAGE_W(cur ^ 1, (t + 1) * 32); }
        bf16x8 af[4], bfr[4];
#pragma unroll
        for (int i = 0; i < 4; ++i) {
            af[i]  = *(const bf16x8*)&As[cur][(wr + i * 16 + m16) * 32 + q8];
            bfr[i] = *(const bf16x8*)&Bs[cur][(wc + i * 16 + m16) * 32 + q8];
        }
#pragma unroll
        for (int i = 0; i < 4; ++i)
#pragma unroll
            for (int j = 0; j < 4; ++j)
                acc[i][j] = __builtin_amdgcn_mfma_f32_16x16x32_bf16(af[i], bfr[j], acc[i][j], 0, 0, 0);
        __syncthreads();
        cur ^= 1;
    }
#undef STAGE_W

    const int rq = (lane >> 4) * 4;
#pragma unroll
    for (int i = 0; i < 4; ++i)
#pragma unroll
        for (int j = 0; j < 4; ++j)
#pragma unroll
            for (int reg = 0; reg < 4; ++reg) {
                int row = rowBase + wr + i * 16 + rq + reg;
                int col = colBase + wc + j * 16 + m16;
                Wbig[(size_t)row * 1024 + col] = f2bf(acc[i][j][reg]);
            }
}

// ---------------------------------------------------------------------------
// PROVEN 128x128 2-phase GEMMs (measured: enc 137us, fused 193us).
// 256 thr = 4 waves (2x2 of 64x64), BK=32, double-buffered LDS (32KB ->
// 5 blocks/CU TLP which hides the per-k-step drain; the 256² variant at
// 2 blocks/CU measured 215us — reverted).
// C/D layout: col=lane&15, row=(lane>>4)*4+reg.
// ---------------------------------------------------------------------------

// ---- encoder: h[n,m] = sigmoid( sum_k xb[n,k]*wencP[m,k] + benc[m] ) ------
__global__ __launch_bounds__(256)
void gemm_enc(const short* __restrict__ Xb, const short* __restrict__ Wp,
              const float* __restrict__ benc, short* __restrict__ H) {
    __shared__ short As[2][128 * 32];
    __shared__ short Bs[2][128 * 32];
    const int tid  = threadIdx.x;
    const int lane = tid & 63;
    const int wave = tid >> 6;
    const int wr   = (wave >> 1) * 64;
    const int wc   = (wave & 1) * 64;
    const u32 swz  = xcd_swz(blockIdx.y * 4 + blockIdx.x, 195, 4);  // nwg=1564
    const int rowBase = (int)(swz >> 2) * 128;
    const int colBase = (int)(swz & 3) * 128;

    floatx4 acc[4][4] = {};

    const int r0 = tid >> 2;
    const int c0 = (tid & 3) * 8;
    int ar0 = rowBase + r0;       if (ar0 >= NNODES) ar0 = NNODES - 1;
    int ar1 = rowBase + r0 + 64;  if (ar1 >= NNODES) ar1 = NNODES - 1;
    const short* aP0 = Xb + (size_t)ar0 * INSZ + c0;
    const short* aP1 = Xb + (size_t)ar1 * INSZ + c0;
    const short* bP0 = Wp + (size_t)(colBase + r0) * INSZ + c0;
    const short* bP1 = Wp + (size_t)(colBase + r0 + 64) * INSZ + c0;

    const int q8  = (lane >> 4) * 8;
    const int m16 = lane & 15;

#define STAGE_E(buf, k0)                                   \
    GLDS16(aP0 + (k0), &As[buf][tid * 8]);                 \
    GLDS16(aP1 + (k0), &As[buf][2048 + tid * 8]);          \
    GLDS16(bP0 + (k0), &Bs[buf][tid * 8]);                 \
    GLDS16(bP1 + (k0), &Bs[buf][2048 + tid * 8]);

    STAGE_E(0, 0);
    __syncthreads();
    int cur = 0;
    for (int t = 0; t < 32; ++t) {
        if (t + 1 < 32) { STAGE_E(cur ^ 1, (t + 1) * 32); }
        bf16x8 af[4], bfr[4];
#pragma unroll
        for (int i = 0; i < 4; ++i) {
            af[i]  = *(const bf16x8*)&As[cur][(wr + i * 16 + m16) * 32 + q8];
            bfr[i] = *(const bf16x8*)&Bs[cur][(wc + i * 16 + m16) * 32 + q8];
        }
#pragma unroll
        for (int i = 0; i < 4; ++i)
#pragma unroll
            for (int j = 0; j < 4; ++j)
                acc[i][j] = __builtin_amdgcn_mfma_f32_16x16x32_bf16(af[i], bfr[j], acc[i][j], 0, 0, 0);
        __syncthreads();
        cur ^= 1;
    }
#undef STAGE_E

    const int rq = (lane >> 4) * 4;
#pragma unroll
    for (int i = 0; i < 4; ++i)
#pragma unroll
        for (int j = 0; j < 4; ++j)
#pragma unroll
            for (int reg = 0; reg < 4; ++reg) {
                int row = rowBase + wr + i * 16 + rq + reg;
                int col = colBase + wc + j * 16 + m16;
                if (row < NNODES) {
                    float b = (col < EMB) ? benc[col] : 0.f;
                    float v = 1.f / (1.f + __expf(-(acc[i][j][reg] + b)));
                    H[(size_t)row * EMBP + col] = f2bf(v);
                }
            }
}

// ---- fused mid+dec: out[n,m] = sum_{k<512} aggB[n,k]*Wbig[m][k]
//                              + sum_{k<512} h[n,k]*Wbig[m][512+k] + bdec[m]
__global__ __launch_bounds__(256)
void gemm_fused(const short* __restrict__ AggB, const short* __restrict__ H,
                const short* __restrict__ Wb, const float* __restrict__ bdec,
                float* __restrict__ Out) {
    __shared__ short As[2][128 * 32];
    __shared__ short Bs[2][128 * 32];
    const int tid  = threadIdx.x;
    const int lane = tid & 63;
    const int wave = tid >> 6;
    const int wr   = (wave >> 1) * 64;
    const int wc   = (wave & 1) * 64;
    const u32 swz  = xcd_swz(blockIdx.y * 8 + blockIdx.x, 391, 0);  // nwg=3128
    const int rowBase = (int)(swz >> 3) * 128;
    const int colBase = (int)(swz & 7) * 128;

    floatx4 acc[4][4] = {};

    const int r0 = tid >> 2;
    const int c0 = (tid & 3) * 8;
    int ar0 = rowBase + r0;       if (ar0 >= NNODES) ar0 = NNODES - 1;
    int ar1 = rowBase + r0 + 64;  if (ar1 >= NNODES) ar1 = NNODES - 1;
    const short* agP0 = AggB + (size_t)ar0 * EMBP + c0;
    const short* agP1 = AggB + (size_t)ar1 * EMBP + c0;
    const short* hP0  = H + (size_t)ar0 * EMBP + c0;
    const short* hP1  = H + (size_t)ar1 * EMBP + c0;
    const short* wP0  = Wb + (size_t)(colBase + r0) * 1024 + c0;
    const short* wP1  = Wb + (size_t)(colBase + r0 + 64) * 1024 + c0;

    const int q8  = (lane >> 4) * 8;
    const int m16 = lane & 15;

#define STAGE_F(buf, k0)                                              \
    if ((k0) < 512) {                                                 \
        GLDS16(agP0 + (k0), &As[buf][tid * 8]);                       \
        GLDS16(agP1 + (k0), &As[buf][2048 + tid * 8]);                \
    } else {                                                          \
        GLDS16(hP0 + ((k0) - 512), &As[buf][tid * 8]);                \
        GLDS16(hP1 + ((k0) - 512), &As[buf][2048 + tid * 8]);         \
    }                                                                 \
    GLDS16(wP0 + (k0), &Bs[buf][tid * 8]);                            \
    GLDS16(wP1 + (k0), &Bs[buf][2048 + tid * 8]);

    STAGE_F(0, 0);
    __syncthreads();
    int cur = 0;
    for (int t = 0; t < 32; ++t) {
        if (t + 1 < 32) { STAGE_F(cur ^ 1, (t + 1) * 32); }
        bf16x8 af[4], bfr[4];
#pragma unroll
        for (int i = 0; i < 4; ++i) {
            af[i]  = *(const bf16x8*)&As[cur][(wr + i * 16 + m16) * 32 + q8];
            bfr[i] = *(const bf16x8*)&Bs[cur][(wc + i * 16 + m16) * 32 + q8];
        }
#pragma unroll
        for (int i = 0; i < 4; ++i)
#pragma unroll
            for (int j = 0; j < 4; ++j)
                acc[i][j] = __builtin_amdgcn_mfma_f32_16x16x32_bf16(af[i], bfr[j], acc[i][j], 0, 0, 0);
        __syncthreads();
        cur ^= 1;
    }
#undef STAGE_F

    const int rq = (lane >> 4) * 4;
#pragma unroll
    for (int i = 0; i < 4; ++i)
#pragma unroll
        for (int j = 0; j < 4; ++j)
#pragma unroll
            for (int reg = 0; reg < 4; ++reg) {
                int row = rowBase + wr + i * 16 + rq + reg;
                int col = colBase + wc + j * 16 + m16;
                if (row < NNODES)
                    Out[(size_t)row * INSZ + col] = acc[i][j][reg] + bdec[col];
            }
}

// ---------------------------------------------------------------------------
// Parallel exclusive scan over counts[50000]: block b re-sums counts[0,b*256)
// then shuffle-scans its own 256. One launch, no cross-block dependency.
// ---------------------------------------------------------------------------
__global__ __launch_bounds__(256)
void scan_counts(const int* __restrict__ counts, int* __restrict__ rowPtr,
                 int* __restrict__ cursor) {
    __shared__ int lsum[4];
    __shared__ int wsc[4];
    const int b = blockIdx.x;            // 196 blocks
    const int t = threadIdx.x;
    const int lane = t & 63;
    const int wv = t >> 6;

    int pre = 0;
    for (int i = t; i < b * 256; i += 256) pre += counts[i];
#pragma unroll
    for (int off = 1; off < 64; off <<= 1) pre += __shfl_xor(pre, off, 64);
    if (lane == 0) lsum[wv] = pre;

    int i = b * 256 + t;
    int c = (i < NNODES) ? counts[i] : 0;
    int v = c;
#pragma unroll
    for (int off = 1; off < 64; off <<= 1) {
        int u = __shfl_up(v, off, 64);
        if (lane >= off) v += u;
    }
    if (lane == 63) wsc[wv] = v;
    __syncthreads();

    int base = lsum[0] + lsum[1] + lsum[2] + lsum[3];
    int woff = 0;
    for (int w = 0; w < wv; ++w) woff += wsc[w];
    if (i < NNODES) {
        int p = base + woff + v - c;
        rowPtr[i] = p;
        cursor[i] = p;
    }
}

__global__ __launch_bounds__(256)
void fill_csr(const int* __restrict__ src, const int* __restrict__ dst,
              const float* __restrict__ ew, int* __restrict__ cursor,
              int* __restrict__ csrSrc, float* __restrict__ csrW) {
    int e = blockIdx.x * 256 + threadIdx.x;
    int d = dst[e];
    int p = atomicAdd(&cursor[d], 1);
    csrSrc[p] = src[e];
    csrW[p]   = ew[e];
}

// gather: one wave per destination node; lane owns 8 of 512 cols.
// 8-deep load pipeline (fully unrolled -> all register indices static).
__global__ __launch_bounds__(256)
void aggregate(const short* __restrict__ H, const int* __restrict__ rowPtr,
               const int* __restrict__ counts, const int* __restrict__ csrSrc,
               const float* __restrict__ csrW, short* __restrict__ aggB) {
    const int n    = blockIdx.x * 4 + (threadIdx.x >> 6);
    const int lane = threadIdx.x & 63;
    const int beg  = rowPtr[n];
    const int cnt  = counts[n];
    const short* hb = H + lane * 8;

    float acc[8] = {0.f, 0.f, 0.f, 0.f, 0.f, 0.f, 0.f, 0.f};
    int i = 0;
    for (; i + 8 <= cnt; i += 8) {
        int   s[8]; float w[8]; bf16x8 v[8];
#pragma unroll
        for (int u = 0; u < 8; ++u) { s[u] = csrSrc[beg + i + u]; w[u] = csrW[beg + i + u]; }
#pragma unroll
        for (int u = 0; u < 8; ++u) v[u] = *(const bf16x8*)(hb + (size_t)s[u] * EMBP);
#pragma unroll
        for (int u = 0; u < 8; ++u)
#pragma unroll
            for (int j = 0; j < 8; ++j)
                acc[j] += w[u] * bf2f(v[u][j]);
    }
    for (; i < cnt; ++i) {
        int   s0 = csrSrc[beg + i];
        float w0 = csrW[beg + i];
        bf16x8 v0 = *(const bf16x8*)(hb + (size_t)s0 * EMBP);
#pragma unroll
        for (int j = 0; j < 8; ++j)
            acc[j] += w0 * bf2f(v0[j]);
    }

    bf16x8 o;
#pragma unroll
    for (int j = 0; j < 8; ++j) o[j] = f2bf(acc[j]);
    *(bf16x8*)(aggB + (size_t)n * EMBP + lane * 8) = o;
}

// ---------------------------------------------------------------------------
extern "C" void kernel_launch(void* const* d_in, const int* in_sizes, int n_in,
                              void* d_out, int out_size, void* d_ws, size_t ws_size,
                              hipStream_t stream) {
    const float* x    = (const float*)d_in[0];
    const int*   ei   = (const int*)d_in[1];
    const float* ew   = (const float*)d_in[2];
    const float* wenc = (const float*)d_in[3];
    const float* benc = (const float*)d_in[4];
    const float* wdec = (const float*)d_in[5];
    const float* bdec = (const float*)d_in[6];
    const float* conv = (const float*)d_in[7];
    const float* lin  = (const float*)d_in[8];
    float* out = (float*)d_out;   // [50000][1024] fp32 = 204.8 MB

    // ws layout (107.7 MB):
    //   0        wencP [512][1024]   1 MB
    //   1 MB     wdecP [1024][512]   1 MB
    //   2 MB     Bw    [1024][512]   1 MB
    //   3 MB     Wbig  [1024][1024]  2 MB
    //   5 MB     h     [50000][512]  51.2 MB
    //   56.2 MB  aggB  [50000][512]  51.2 MB  (must NOT alias d_out:
    //            gemm_fused reads it while writing all of d_out)
    char* ws = (char*)d_ws;
    short* wencP = (short*)(ws);
    short* wdecP = (short*)(ws + 1048576);
    short* Bw    = (short*)(ws + 2097152);
    short* Wbig  = (short*)(ws + 3145728);
    short* h     = (short*)(ws + 5242880);
    short* aggB  = (short*)(ws + 5242880 + 51200000);

    // d_out is dead until gemm_fused's final overwrite:
    //   FIRST half  [0, 7MB):       CSR scratch (counts/rowPtr/cursor/csr)
    //   SECOND half [102.4, 204.8): Xbf bf16 [50000][1024]
    char*  scratch = (char*)d_out;
    int*   counts = (int*)scratch;
    int*   rowPtr = counts + NNODES;
    int*   cursor = rowPtr + NNODES;
    int*   csrSrc = cursor + NNODES;
    float* csrW   = (float*)(csrSrc + NEDGES);
    short* Xbf    = (short*)((char*)d_out + 102400000);

    dim3 blk(256);
    hipMemsetAsync(counts, 0, (size_t)NNODES * 4, stream);

    // conv_x + weight packing + dst histogram, one launch
    prep<<<25000, blk, 0, stream>>>(x, wenc, conv, lin, wdec, ei + NEDGES,
                                    Xbf, wencP, wdecP, Bw, counts);

    // Wbig = wdec (x) [conv | lin^T]  (M=N=1024, K=512)
    gemm_wpre<<<dim3(8, 8), blk, 0, stream>>>(wdecP, Bw, Wbig);

    // rowPtr/cursor from counts (parallel, one launch)
    scan_counts<<<196, blk, 0, stream>>>(counts, rowPtr, cursor);
    fill_csr<<<NEDGES / 256, blk, 0, stream>>>(ei, ei + NEDGES, ew, cursor, csrSrc, csrW);

    // h = sigmoid(xb @ wenc^T + benc)   (proven 128² body, 137us)
    gemm_enc<<<dim3(EMBP / 128, (NNODES + 127) / 128), blk, 0, stream>>>(Xbf, wencP, benc, h);

    // agg[n] = sum_{in-edges} w * h[src]
    aggregate<<<NNODES / 4, blk, 0, stream>>>(h, rowPtr, counts, csrSrc, csrW, aggB);

    // out = aggB @ Wbig[:, :512]^T + h @ Wbig[:, 512:]^T + bdec  (proven 128², 193us)
    gemm_fused<<<dim3(INSZ / 128, (NNODES + 127) / 128), blk, 0, stream>>>(aggB, h, Wbig, bdec, out);
}